// Round 2
// baseline (103.513 us; speedup 1.0000x reference)
//
#include <hip/hip_runtime.h>

#define MAX_SPIKE 100000.0f

constexpr int BATCH = 128;
constexpr int NIN   = 1024;
constexpr int MOUT  = 512;
constexpr int T     = 256;   // threads per block
constexpr int MPB   = 256;   // m-columns per block
constexpr int CH    = 8;     // chunk (prefetch granularity)

__global__ __launch_bounds__(T) void snn_fc_kernel(const float* __restrict__ x,
                                                   const float* __restrict__ w,
                                                   float* __restrict__ out) {
    // Bit-exact vs numpy float32: no FMA contraction anywhere in this kernel.
    #pragma clang fp contract(off)

    __shared__ unsigned long long keys[NIN];
    __shared__ float xs[NIN + 1];
    __shared__ int   roff[NIN];   // sorted row index * MOUT

    const int tid = threadIdx.x;
    const int b   = blockIdx.x >> 1;
    const int mo  = ((blockIdx.x & 1) ? MPB : 0) + tid;

    // keys = (float_bits << 32) | index: x >= 0 so uint order == float order,
    // low index bits reproduce stable argsort tie-breaking.
    for (int i = tid; i < NIN; i += T) {
        unsigned int bits = __float_as_uint(x[b * NIN + i]);
        keys[i] = ((unsigned long long)bits << 32) | (unsigned int)i;
    }
    __syncthreads();

    // Bitonic sort ascending; pairs within a (k,j) stage are disjoint.
    for (int k = 2; k <= NIN; k <<= 1) {
        for (int j = k >> 1; j > 0; j >>= 1) {
            #pragma unroll
            for (int r = 0; r < NIN / T; ++r) {
                int i = tid + r * T;
                int ixj = i ^ j;
                if (ixj > i) {
                    unsigned long long a = keys[i], c = keys[ixj];
                    bool asc = ((i & k) == 0);
                    if ((a > c) == asc) { keys[i] = c; keys[ixj] = a; }
                }
            }
            __syncthreads();
        }
    }

    for (int i = tid; i < NIN; i += T) {
        unsigned long long kk = keys[i];
        xs[i]   = __uint_as_float((unsigned int)(kk >> 32));
        roff[i] = (int)(kk & 0xFFFFFFFFull) * MOUT;
    }
    if (tid == 0) xs[NIN] = MAX_SPIKE;
    __syncthreads();

    // Sequential scan, one m-column per thread — LITERAL port of the reference:
    //   d    = clip(w_cum - 1, 1e-10, 1e10)
    //   q    = wi_cum / d                      (IEEE f32 division)
    //   cand = MAX if (w_cum < 1) | (q < xs[n]) | (q > xs[n+1]) else q
    //   best = min(best, cand)
    float wcum = 0.0f, wicum = 0.0f, best = MAX_SPIKE;
    float xprev = xs[0];

    const float* __restrict__ wcol = w + mo;
    float wA[CH], wB[CH];

    #pragma unroll
    for (int u = 0; u < CH; ++u) wA[u] = wcol[roff[u]];

    constexpr int NCH = NIN / CH;  // 128

    for (int c = 0; c < NCH; c += 2) {
        const int base1 = (c + 1) * CH;
        #pragma unroll
        for (int u = 0; u < CH; ++u) wB[u] = wcol[roff[base1 + u]];

        #pragma unroll
        for (int u = 0; u < CH; ++u) {
            float ww = wA[u];
            float xv = xprev;
            float xl = xs[c * CH + u + 1];
            wcum  = wcum + ww;
            wicum = wicum + ww * xv;          // round product, then add (np order)
            float d = fminf(fmaxf(wcum - 1.0f, 1e-10f), 1e10f);
            float q = wicum / d;
            float cand = (wcum < 1.0f || q < xv || q > xl) ? MAX_SPIKE : q;
            best = fminf(best, cand);
            xprev = xl;
        }

        if (c + 2 < NCH) {
            const int base2 = (c + 2) * CH;
            #pragma unroll
            for (int u = 0; u < CH; ++u) wA[u] = wcol[roff[base2 + u]];
        }

        #pragma unroll
        for (int u = 0; u < CH; ++u) {
            float ww = wB[u];
            float xv = xprev;
            float xl = xs[base1 + u + 1];
            wcum  = wcum + ww;
            wicum = wicum + ww * xv;
            float d = fminf(fmaxf(wcum - 1.0f, 1e-10f), 1e10f);
            float q = wicum / d;
            float cand = (wcum < 1.0f || q < xv || q > xl) ? MAX_SPIKE : q;
            best = fminf(best, cand);
            xprev = xl;
        }
    }

    out[b * MOUT + mo] = best;
}

extern "C" void kernel_launch(void* const* d_in, const int* in_sizes, int n_in,
                              void* d_out, int out_size, void* d_ws, size_t ws_size,
                              hipStream_t stream) {
    (void)in_sizes; (void)n_in; (void)d_ws; (void)ws_size; (void)out_size;
    const float* x = (const float*)d_in[0];
    const float* w = (const float*)d_in[1];
    float* out = (float*)d_out;

    dim3 grid(BATCH * (MOUT / MPB));  // 256 blocks
    dim3 block(T);
    hipLaunchKernelGGL(snn_fc_kernel, grid, block, 0, stream, x, w, out);
}

// Round 3
// 96.420 us; speedup vs baseline: 1.0736x; 1.0736x over previous
//
#include <hip/hip_runtime.h>

#define MAX_SPIKE 100000.0f

constexpr int BATCH  = 128;
constexpr int NIN    = 1024;
constexpr int MOUT   = 512;
constexpr int T      = 256;           // 4 waves per block
constexpr int NWAVE  = 4;             // n-segments == waves
constexpr int SEGLEN = NIN / NWAVE;   // 256
constexpr int CPB    = 64;            // columns per block (one per lane)
constexpr int CH     = 8;             // prefetch chunk

__global__ __launch_bounds__(T) void snn_fc_kernel(const float* __restrict__ x,
                                                   const float* __restrict__ w,
                                                   float* __restrict__ out) {
    // Bit-exact vs numpy float32: no FMA contraction anywhere.
    #pragma clang fp contract(off)

    __shared__ unsigned long long keys[NIN];
    __shared__ float xs[NIN + 1];
    __shared__ int   roff[NIN];
    __shared__ float bestsh[NWAVE][CPB];

    const int tid  = threadIdx.x;
    const int b    = blockIdx.x >> 3;        // 8 col-groups per batch row
    const int cg   = blockIdx.x & 7;
    const int wave = tid >> 6;               // n-segment owned by this wave
    const int lane = tid & 63;
    const int mo   = cg * CPB + lane;        // this thread's output column

    // ---- keys = (float_bits << 32) | index: x >= 0 so uint order == float
    //      order; low bits reproduce stable argsort tie-breaking.
    for (int i = tid; i < NIN; i += T) {
        unsigned int bits = __float_as_uint(x[b * NIN + i]);
        keys[i] = ((unsigned long long)bits << 32) | (unsigned int)i;
    }
    __syncthreads();

    // ---- bitonic sort ascending (disjoint pairs within each (k,j) stage)
    for (int k = 2; k <= NIN; k <<= 1) {
        for (int j = k >> 1; j > 0; j >>= 1) {
            #pragma unroll
            for (int r = 0; r < NIN / T; ++r) {
                int i = tid + r * T;
                int ixj = i ^ j;
                if (ixj > i) {
                    unsigned long long a = keys[i], c2 = keys[ixj];
                    bool asc = ((i & k) == 0);
                    if ((a > c2) == asc) { keys[i] = c2; keys[ixj] = a; }
                }
            }
            __syncthreads();
        }
    }

    for (int i = tid; i < NIN; i += T) {
        unsigned long long kk = keys[i];
        xs[i]   = __uint_as_float((unsigned int)(kk >> 32));
        roff[i] = (int)(kk & 0xFFFFFFFFull) * MOUT;
    }
    if (tid == 0) xs[NIN] = MAX_SPIKE;
    __syncthreads();

    const float* __restrict__ wcol = w + mo;
    float wcum = 0.0f, wicum = 0.0f, best = MAX_SPIKE;
    float wA[CH], wB[CH];

    // ---- phase 1: exact sequential prefix over [0, wave*SEGLEN).
    // Same element order + same rounding as the reference cumsum, so the
    // segment base is bit-identical to the sequential partial. No division.
    const int nch1 = (wave * SEGLEN) / CH;   // 0, 32, 64, 96 (all even)
    if (nch1 > 0) {
        #pragma unroll
        for (int u = 0; u < CH; ++u) wA[u] = wcol[roff[u]];
        for (int c = 0; c < nch1; c += 2) {
            const int b1 = (c + 1) * CH;
            #pragma unroll
            for (int u = 0; u < CH; ++u) wB[u] = wcol[roff[b1 + u]];
            #pragma unroll
            for (int u = 0; u < CH; ++u) {
                float ww = wA[u];
                wcum  = wcum + ww;
                wicum = wicum + ww * xs[c * CH + u];   // round mul, then add
            }
            if (c + 2 < nch1) {
                const int b2 = (c + 2) * CH;
                #pragma unroll
                for (int u = 0; u < CH; ++u) wA[u] = wcol[roff[b2 + u]];
            }
            #pragma unroll
            for (int u = 0; u < CH; ++u) {
                float ww = wB[u];
                wcum  = wcum + ww;
                wicum = wicum + ww * xs[b1 + u];
            }
        }
    }

    // ---- phase 2: full candidate scan on own segment [n0, n0+SEGLEN)
    const int n0 = wave * SEGLEN;
    float xprev = xs[n0];
    #pragma unroll
    for (int u = 0; u < CH; ++u) wA[u] = wcol[roff[n0 + u]];

    constexpr int NCH2 = SEGLEN / CH;        // 32 (even)
    for (int c = 0; c < NCH2; c += 2) {
        const int b1 = n0 + (c + 1) * CH;
        #pragma unroll
        for (int u = 0; u < CH; ++u) wB[u] = wcol[roff[b1 + u]];

        #pragma unroll
        for (int u = 0; u < CH; ++u) {
            float ww = wA[u];
            float xv = xprev;
            float xl = xs[n0 + c * CH + u + 1];
            wcum  = wcum + ww;
            wicum = wicum + ww * xv;
            float d = fminf(fmaxf(wcum - 1.0f, 1e-10f), 1e10f);
            float q = wicum / d;               // IEEE f32 division (matches np)
            float cand = (wcum < 1.0f || q < xv || q > xl) ? MAX_SPIKE : q;
            best = fminf(best, cand);
            xprev = xl;
        }

        if (c + 2 < NCH2) {
            const int b2 = n0 + (c + 2) * CH;
            #pragma unroll
            for (int u = 0; u < CH; ++u) wA[u] = wcol[roff[b2 + u]];
        }

        #pragma unroll
        for (int u = 0; u < CH; ++u) {
            float ww = wB[u];
            float xv = xprev;
            float xl = xs[b1 + u + 1];
            wcum  = wcum + ww;
            wicum = wicum + ww * xv;
            float d = fminf(fmaxf(wcum - 1.0f, 1e-10f), 1e10f);
            float q = wicum / d;
            float cand = (wcum < 1.0f || q < xv || q > xl) ? MAX_SPIKE : q;
            best = fminf(best, cand);
            xprev = xl;
        }
    }

    // ---- cross-segment min (MAX_SPIKE-padded segments reduce correctly)
    bestsh[wave][lane] = best;
    __syncthreads();
    if (tid < CPB) {
        float r0 = fminf(fminf(bestsh[0][tid], bestsh[1][tid]),
                         fminf(bestsh[2][tid], bestsh[3][tid]));
        out[b * MOUT + cg * CPB + tid] = r0;
    }
}

extern "C" void kernel_launch(void* const* d_in, const int* in_sizes, int n_in,
                              void* d_out, int out_size, void* d_ws, size_t ws_size,
                              hipStream_t stream) {
    (void)in_sizes; (void)n_in; (void)d_ws; (void)ws_size; (void)out_size;
    const float* x = (const float*)d_in[0];
    const float* w = (const float*)d_in[1];
    float* out = (float*)d_out;

    dim3 grid(BATCH * (MOUT / CPB));   // 128 * 8 = 1024 blocks (4 per CU)
    dim3 block(T);
    hipLaunchKernelGGL(snn_fc_kernel, grid, block, 0, stream, x, w, out);
}

// Round 4
// 71.484 us; speedup vs baseline: 1.4481x; 1.3488x over previous
//
#include <hip/hip_runtime.h>

#define MAX_SPIKE 100000.0f

constexpr int BATCH  = 128;
constexpr int NIN    = 1024;
constexpr int MOUT   = 512;
constexpr int T      = 256;           // 4 waves per block
constexpr int NWAVE  = 4;             // n-segments
constexpr int SEGLEN = NIN / NWAVE;   // 256
constexpr int CPB    = 64;            // columns per block (one per lane)
constexpr int CH     = 8;             // prefetch chunk

// ---------------- kernel 1: per-row stable argsort (once per row) ----------
__global__ __launch_bounds__(T) void snn_sort_kernel(const float* __restrict__ x,
                                                     float* __restrict__ xs_g,
                                                     int* __restrict__ roff4_g) {
    __shared__ unsigned long long keys[NIN];
    const int tid = threadIdx.x;
    const int b   = blockIdx.x;

    // keys = (float_bits << 32) | index: x >= 0 so uint order == float order;
    // low index bits reproduce stable argsort tie-breaking.
    for (int i = tid; i < NIN; i += T) {
        unsigned int bits = __float_as_uint(x[b * NIN + i]);
        keys[i] = ((unsigned long long)bits << 32) | (unsigned int)i;
    }
    __syncthreads();

    for (int k = 2; k <= NIN; k <<= 1) {
        for (int j = k >> 1; j > 0; j >>= 1) {
            #pragma unroll
            for (int r = 0; r < NIN / T; ++r) {
                int i = tid + r * T;
                int ixj = i ^ j;
                if (ixj > i) {
                    unsigned long long a = keys[i], c2 = keys[ixj];
                    bool asc = ((i & k) == 0);
                    if ((a > c2) == asc) { keys[i] = c2; keys[ixj] = a; }
                }
            }
            __syncthreads();
        }
    }

    for (int i = tid; i < NIN; i += T) {
        unsigned long long kk = keys[i];
        xs_g[b * (NIN + 1) + i] = __uint_as_float((unsigned int)(kk >> 32));
        roff4_g[b * NIN + i]    = (int)(kk & 0xFFFFFFFFull) * (MOUT * 4); // byte offset
    }
    if (tid == 0) xs_g[b * (NIN + 1) + NIN] = MAX_SPIKE;
}

// ---------------- kernel 2: segmented scan with screened division ----------
__global__ __launch_bounds__(T) void snn_scan_kernel(const float* __restrict__ w,
                                                     const float* __restrict__ xs_g,
                                                     const int* __restrict__ roff4_g,
                                                     float* __restrict__ out) {
    // Exact-path arithmetic must match numpy f32: no FMA contraction.
    #pragma clang fp contract(off)

    __shared__ float xs[NIN + 1];
    __shared__ int   roff4[NIN];
    __shared__ float bestsh[NWAVE][CPB];

    const int tid  = threadIdx.x;
    const int b    = blockIdx.x >> 3;
    const int cg   = blockIdx.x & 7;
    const int wave = tid >> 6;
    const int lane = tid & 63;
    // Swizzle segment ownership so long/short prefix waves mix across SIMDs.
    const int seg  = (wave + blockIdx.x) & (NWAVE - 1);
    const int mo4  = (cg * CPB + lane) * 4;

    for (int i = tid; i < NIN + 1; i += T) xs[i] = xs_g[b * (NIN + 1) + i];
    for (int i = tid; i < NIN; i += T)     roff4[i] = roff4_g[b * NIN + i];
    __syncthreads();

    const char* wb = (const char*)w;
    float wcum = 0.0f, wicum = 0.0f, best = MAX_SPIKE;
    float wA[CH], wB[CH];

#define LOADC(dst, base_) { const int bb_ = (base_); _Pragma("unroll") \
    for (int u = 0; u < CH; ++u) \
        dst[u] = *(const float*)(wb + (unsigned)(roff4[bb_ + u] + mo4)); }

    // ---- phase 1: exact sequential prefix over [0, seg*SEGLEN); no division.
    const int nch1 = seg * (SEGLEN / CH);
    if (nch1 > 0) {
        LOADC(wA, 0);
        for (int c = 0; c < nch1; c += 2) {
            LOADC(wB, (c + 1) * CH);
            #pragma unroll
            for (int u = 0; u < CH; ++u) {
                float ww = wA[u];
                wcum  = wcum + ww;
                wicum = wicum + ww * xs[c * CH + u];   // round mul, then add
            }
            if (c + 2 < nch1) LOADC(wA, (c + 2) * CH);
            #pragma unroll
            for (int u = 0; u < CH; ++u) {
                float ww = wB[u];
                wcum  = wcum + ww;
                wicum = wicum + ww * xs[(c + 1) * CH + u];
            }
        }
    }

    // ---- phase 2: candidate scan on own segment with conservative screen.
    // Skip is taken only when exact path PROVABLY yields MAX_SPIKE:
    //   wicum < (xv*d)*(1-8e-7)  =>  q < xv   (1-ulp-safe, all values >= 0)
    //   wicum > (xl*d)*(1+8e-7)  =>  q > xl
    // Borderline lanes fall into the exact IEEE-division reference path.
    const int n0 = seg * SEGLEN;
    float xprev = xs[n0];
    LOADC(wA, n0);

#define SCAN_STEP(ww_, n_) { \
    float xv = xprev; \
    float xl = xs[(n_) + 1]; \
    wcum  = wcum + (ww_); \
    wicum = wicum + (ww_) * xv; \
    float d = fmaxf(wcum - 1.0f, 1e-10f); /* upper clip 1e10 never binds: wcum<=~4.3 */ \
    bool pot = (wcum >= 1.0f) && (wicum >= (xv * d) * (1.0f - 8e-7f)) \
                              && (wicum <= (xl * d) * (1.0f + 8e-7f)); \
    if (pot) { \
        float q = wicum / d;                 /* IEEE f32 division (matches np) */ \
        float cand = (q < xv || q > xl) ? MAX_SPIKE : q; \
        best = fminf(best, cand); \
    } \
    xprev = xl; }

    constexpr int NCH2 = SEGLEN / CH;        // 32 (even)
    for (int c = 0; c < NCH2; c += 2) {
        const int b1 = n0 + (c + 1) * CH;
        LOADC(wB, b1);
        #pragma unroll
        for (int u = 0; u < CH; ++u) SCAN_STEP(wA[u], n0 + c * CH + u);
        if (c + 2 < NCH2) LOADC(wA, n0 + (c + 2) * CH);
        #pragma unroll
        for (int u = 0; u < CH; ++u) SCAN_STEP(wB[u], b1 + u);
    }
#undef SCAN_STEP
#undef LOADC

    bestsh[wave][lane] = best;
    __syncthreads();
    if (tid < CPB) {
        float r0 = fminf(fminf(bestsh[0][tid], bestsh[1][tid]),
                         fminf(bestsh[2][tid], bestsh[3][tid]));
        out[b * MOUT + cg * CPB + tid] = r0;
    }
}

// ---------------- fallback: round-3 fused kernel (if ws too small) ---------
__global__ __launch_bounds__(T) void snn_fc_fused(const float* __restrict__ x,
                                                  const float* __restrict__ w,
                                                  float* __restrict__ out) {
    #pragma clang fp contract(off)
    __shared__ unsigned long long keys[NIN];
    __shared__ float xs[NIN + 1];
    __shared__ int   roff[NIN];
    __shared__ float bestsh[NWAVE][CPB];

    const int tid  = threadIdx.x;
    const int b    = blockIdx.x >> 3;
    const int cg   = blockIdx.x & 7;
    const int wave = tid >> 6;
    const int lane = tid & 63;
    const int mo   = cg * CPB + lane;

    for (int i = tid; i < NIN; i += T) {
        unsigned int bits = __float_as_uint(x[b * NIN + i]);
        keys[i] = ((unsigned long long)bits << 32) | (unsigned int)i;
    }
    __syncthreads();
    for (int k = 2; k <= NIN; k <<= 1)
        for (int j = k >> 1; j > 0; j >>= 1) {
            #pragma unroll
            for (int r = 0; r < NIN / T; ++r) {
                int i = tid + r * T, ixj = i ^ j;
                if (ixj > i) {
                    unsigned long long a = keys[i], c2 = keys[ixj];
                    bool asc = ((i & k) == 0);
                    if ((a > c2) == asc) { keys[i] = c2; keys[ixj] = a; }
                }
            }
            __syncthreads();
        }
    for (int i = tid; i < NIN; i += T) {
        unsigned long long kk = keys[i];
        xs[i]   = __uint_as_float((unsigned int)(kk >> 32));
        roff[i] = (int)(kk & 0xFFFFFFFFull) * MOUT;
    }
    if (tid == 0) xs[NIN] = MAX_SPIKE;
    __syncthreads();

    const float* __restrict__ wcol = w + mo;
    float wcum = 0.0f, wicum = 0.0f, best = MAX_SPIKE;

    for (int n = 0; n < wave * SEGLEN; ++n) {
        float ww = wcol[roff[n]];
        wcum = wcum + ww;
        wicum = wicum + ww * xs[n];
    }
    const int n0 = wave * SEGLEN;
    float xprev = xs[n0];
    for (int n = n0; n < n0 + SEGLEN; ++n) {
        float ww = wcol[roff[n]];
        float xv = xprev, xl = xs[n + 1];
        wcum = wcum + ww;
        wicum = wicum + ww * xv;
        float d = fminf(fmaxf(wcum - 1.0f, 1e-10f), 1e10f);
        float q = wicum / d;
        float cand = (wcum < 1.0f || q < xv || q > xl) ? MAX_SPIKE : q;
        best = fminf(best, cand);
        xprev = xl;
    }
    bestsh[wave][lane] = best;
    __syncthreads();
    if (tid < CPB) {
        float r0 = fminf(fminf(bestsh[0][tid], bestsh[1][tid]),
                         fminf(bestsh[2][tid], bestsh[3][tid]));
        out[b * MOUT + cg * CPB + tid] = r0;
    }
}

extern "C" void kernel_launch(void* const* d_in, const int* in_sizes, int n_in,
                              void* d_out, int out_size, void* d_ws, size_t ws_size,
                              hipStream_t stream) {
    (void)in_sizes; (void)n_in; (void)out_size;
    const float* x = (const float*)d_in[0];
    const float* w = (const float*)d_in[1];
    float* out = (float*)d_out;

    const size_t xs_bytes  = (size_t)BATCH * (NIN + 1) * sizeof(float);
    const size_t off_bytes = (size_t)BATCH * NIN * sizeof(int);

    if (ws_size >= xs_bytes + off_bytes) {
        float* xs_g   = (float*)d_ws;
        int*   roff4g = (int*)((char*)d_ws + xs_bytes);
        hipLaunchKernelGGL(snn_sort_kernel, dim3(BATCH), dim3(T), 0, stream,
                           x, xs_g, roff4g);
        hipLaunchKernelGGL(snn_scan_kernel, dim3(BATCH * (MOUT / CPB)), dim3(T),
                           0, stream, w, xs_g, roff4g, out);
    } else {
        hipLaunchKernelGGL(snn_fc_fused, dim3(BATCH * (MOUT / CPB)), dim3(T),
                           0, stream, x, w, out);
    }
}